// Round 1
// baseline (3769.069 us; speedup 1.0000x reference)
//
#include <hip/hip_runtime.h>
#include <hip/hip_bf16.h>

#define DIMN  256
#define NOBJ  16384
#define NPAIR 131072

typedef float  floatx4 __attribute__((ext_vector_type(4)));
typedef __bf16 bf16x8  __attribute__((ext_vector_type(8)));

static __device__ __forceinline__ unsigned short f2bf(float f) {
  unsigned u = __builtin_bit_cast(unsigned, f);
  u += 0x7FFFu + ((u >> 16) & 1u);          // round-to-nearest-even
  return (unsigned short)(u >> 16);
}
static __device__ __forceinline__ float sigmoidf_(float x) {
  return 1.0f / (1.0f + __expf(-x));
}
static __device__ __forceinline__ float tanhf_(float x) {
  return 1.0f - 2.0f / (1.0f + __expf(2.0f * x));
}
static __device__ __forceinline__ float dot4(float4 a, float4 b) {
  return a.x*b.x + a.y*b.y + a.z*b.z + a.w*b.w;
}
static __device__ __forceinline__ float4 relu4(float4 a) {
  float4 r; r.x = fmaxf(a.x,0.f); r.y = fmaxf(a.y,0.f);
  r.z = fmaxf(a.z,0.f); r.w = fmaxf(a.w,0.f); return r;
}
static __device__ __forceinline__ floatx4 mfma16(bf16x8 a, bf16x8 b, floatx4 c) {
  return __builtin_amdgcn_mfma_f32_16x16x32_bf16(a, b, c, 0, 0, 0);
}

// ---------------------------------------------------------------------------
// weight fp32 -> bf16 conversion (once per launch). out: [wih | whh] bf16.
__global__ __launch_bounds__(256) void conv_w(const float* __restrict__ wih,
                                              const float* __restrict__ whh,
                                              unsigned short* __restrict__ out) {
  int i = blockIdx.x * 256 + threadIdx.x;           // one float4 each; 98304 total
  float4 v;
  if (i < 49152) v = ((const float4*)wih)[i];
  else           v = ((const float4*)whh)[i - 49152];
  unsigned short* d = out + (size_t)i * 4;
  d[0] = f2bf(v.x); d[1] = f2bf(v.y); d[2] = f2bf(v.z); d[3] = f2bf(v.w);
}

// ---------------------------------------------------------------------------
// Per-pair gate kernel: one wave per pair. Computes the 4 gate scalars,
// atomically accumulates msg (segment-sum) and writes xg = m_s2p + m_o2p.
__global__ __launch_bounds__(256) void gate_kernel(
    const float* __restrict__ xobj, const float* __restrict__ xpred,
    const int* __restrict__ pairs,
    const float* __restrict__ w_e2v, const float* __restrict__ b_e2v,
    const float* __restrict__ w_v2e, const float* __restrict__ b_v2e,
    float* __restrict__ msg, float* __restrict__ xg)
{
  const int wave = threadIdx.x >> 6;
  const int lane = threadIdx.x & 63;
  const int p = blockIdx.x * 4 + wave;
  const int s = pairs[2*p], o = pairs[2*p+1];

  float4 vp = ((const float4*)(xpred + (size_t)p*DIMN))[lane];
  float4 vs = ((const float4*)(xobj  + (size_t)s*DIMN))[lane];
  float4 vo = ((const float4*)(xobj  + (size_t)o*DIMN))[lane];
  float4 we0 = ((const float4*)w_e2v)[lane];
  float4 we1 = ((const float4*)w_e2v)[64 + lane];
  float4 wv0 = ((const float4*)w_v2e)[lane];
  float4 wv1 = ((const float4*)w_v2e)[64 + lane];

  float4 rp = relu4(vp), rs = relu4(vs), ro = relu4(vo);
  float t0 = dot4(rs, we0);   // relu(x_obj[s]) . we[0:256]
  float t1 = dot4(ro, we0);   // relu(x_obj[o]) . we[0:256]
  float t2 = dot4(rp, we1);   // relu(x_pred)   . we[256:512]
  float t3 = dot4(rp, wv0);   // relu(x_pred)   . wv[0:256]
  float t4 = dot4(rs, wv1);   // relu(x_obj[s]) . wv[256:512]
  float t5 = dot4(ro, wv1);   // relu(x_obj[o]) . wv[256:512]
  #pragma unroll
  for (int off = 32; off >= 1; off >>= 1) {
    t0 += __shfl_xor(t0, off); t1 += __shfl_xor(t1, off);
    t2 += __shfl_xor(t2, off); t3 += __shfl_xor(t3, off);
    t4 += __shfl_xor(t4, off); t5 += __shfl_xor(t5, off);
  }
  const float be = b_e2v[0], bv = b_v2e[0];
  const float g_s  = sigmoidf_(t0 + t2 + be);
  const float g_o  = sigmoidf_(t1 + t2 + be);
  const float g_sp = sigmoidf_(t3 + t4 + bv);
  const float g_op = sigmoidf_(t3 + t5 + bv);

  float4 xgv;
  xgv.x = vs.x*g_sp + vo.x*g_op; xgv.y = vs.y*g_sp + vo.y*g_op;
  xgv.z = vs.z*g_sp + vo.z*g_op; xgv.w = vs.w*g_sp + vo.w*g_op;
  ((float4*)(xg + (size_t)p*DIMN))[lane] = xgv;

  float* ms = msg + (size_t)s*DIMN + lane*4;
  unsafeAtomicAdd(ms+0, vp.x*g_s); unsafeAtomicAdd(ms+1, vp.y*g_s);
  unsafeAtomicAdd(ms+2, vp.z*g_s); unsafeAtomicAdd(ms+3, vp.w*g_s);
  float* mo = msg + (size_t)o*DIMN + lane*4;
  unsafeAtomicAdd(mo+0, vp.x*g_o); unsafeAtomicAdd(mo+1, vp.y*g_o);
  unsafeAtomicAdd(mo+2, vp.z*g_o); unsafeAtomicAdd(mo+3, vp.w*g_o);
}

// ---------------------------------------------------------------------------
// Fused GRU: out = (1-z)*tanh(i_n + r*h_n) + z*h,  r/z from fused K=512 GEMM.
// Workgroup = 64 rows x all 256 cols (16 waves: 4 row-groups x 4 col-groups).
// Owns full rows -> in-place (OUT==H) is race-free.
#define LDSS 56   // ushorts per LDS row (112 B: 16B-aligned, 2-way banks only)
__global__ __launch_bounds__(1024) void gru_kernel(
    const float* __restrict__ X, const float* __restrict__ H,
    const unsigned short* __restrict__ Wih, const unsigned short* __restrict__ Whh,
    const float* __restrict__ b_ih, const float* __restrict__ b_hh,
    float* __restrict__ OUT)
{
  __shared__ unsigned short Xs[64 * LDSS];
  __shared__ unsigned short Hs[64 * LDSS];

  const int tid  = threadIdx.x;
  const int lane = tid & 63;
  const int wave = tid >> 6;          // 0..15
  const int wr   = wave >> 2;         // row group (16 rows each)
  const int wc   = wave & 3;          // col group (64 cols each)
  const int rowBase = blockIdx.x * 64;
  const int colBase = wc * 64;
  const int quad = lane >> 4;         // 0..3
  const int l16  = lane & 15;

  floatx4 acc_r[4], acc_z[4], acc_in[4], acc_hn[4];
  #pragma unroll
  for (int c = 0; c < 4; c++) {
    acc_r[c] = (floatx4){0,0,0,0}; acc_z[c] = (floatx4){0,0,0,0};
    acc_in[c] = (floatx4){0,0,0,0}; acc_hn[c] = (floatx4){0,0,0,0};
  }

  // staging assignment: 1024 thr = 2 matrices x 64 rows x 8 float4-chunks
  const int sel = tid >> 9, rem = tid & 511;
  const int srow = rem >> 3, skq = (rem & 7) << 2;    // skq in {0,4,...,28}
  const float* src = sel ? H : X;
  unsigned short* dst = (sel ? Hs : Xs) + srow * LDSS + skq;
  const float* srcRow = src + (size_t)(rowBase + srow) * DIMN + skq;

  const int aoff = (wr*16 + l16) * LDSS + (quad << 3);

  for (int kc = 0; kc < 8; kc++) {
    float4 v = *(const float4*)(srcRow + kc*32);
    unsigned pk0 = (unsigned)f2bf(v.x) | ((unsigned)f2bf(v.y) << 16);
    unsigned pk1 = (unsigned)f2bf(v.z) | ((unsigned)f2bf(v.w) << 16);
    *(uint2*)dst = make_uint2(pk0, pk1);
    __syncthreads();

    bf16x8 aX = *(const bf16x8*)(Xs + aoff);
    bf16x8 aH = *(const bf16x8*)(Hs + aoff);
    const int k0 = kc * 32 + (quad << 3);
    #pragma unroll
    for (int c = 0; c < 4; c++) {
      const int n = colBase + c*16 + l16;
      const unsigned short* bih = Wih + (size_t)n * DIMN + k0;
      const unsigned short* bhh = Whh + (size_t)n * DIMN + k0;
      acc_r[c]  = mfma16(aX, *(const bf16x8*)(bih),            acc_r[c]);
      acc_r[c]  = mfma16(aH, *(const bf16x8*)(bhh),            acc_r[c]);
      acc_z[c]  = mfma16(aX, *(const bf16x8*)(bih + 256*DIMN), acc_z[c]);
      acc_z[c]  = mfma16(aH, *(const bf16x8*)(bhh + 256*DIMN), acc_z[c]);
      acc_in[c] = mfma16(aX, *(const bf16x8*)(bih + 512*DIMN), acc_in[c]);
      acc_hn[c] = mfma16(aH, *(const bf16x8*)(bhh + 512*DIMN), acc_hn[c]);
    }
    __syncthreads();
  }

  // epilogue: C layout col=lane&15, row=quad*4+reg (m89-verified)
  const int m0 = rowBase + wr*16 + (quad << 2);
  #pragma unroll
  for (int c = 0; c < 4; c++) {
    const int j = colBase + c*16 + l16;
    const float br = b_ih[j]       + b_hh[j];
    const float bz = b_ih[j + 256] + b_hh[j + 256];
    const float bi_n = b_ih[j + 512], bh_n = b_hh[j + 512];
    #pragma unroll
    for (int v = 0; v < 4; v++) {
      const size_t idx = (size_t)(m0 + v) * DIMN + j;
      const float r_ = sigmoidf_(acc_r[c][v] + br);
      const float z_ = sigmoidf_(acc_z[c][v] + bz);
      const float n_ = tanhf_(acc_in[c][v] + bi_n + r_ * (acc_hn[c][v] + bh_n));
      const float h  = H[idx];
      OUT[idx] = (1.0f - z_) * n_ + z_ * h;
    }
  }
}

// ---------------------------------------------------------------------------
extern "C" void kernel_launch(void* const* d_in, const int* in_sizes, int n_in,
                              void* d_out, int out_size, void* d_ws, size_t ws_size,
                              hipStream_t stream) {
  const float* x_obj  = (const float*)d_in[0];
  const float* x_pred = (const float*)d_in[1];
  const int*   pairs  = (const int*)d_in[2];
  const float* w_e2v  = (const float*)d_in[3];
  const float* b_e2v  = (const float*)d_in[4];
  const float* w_v2e  = (const float*)d_in[5];
  const float* b_v2e  = (const float*)d_in[6];
  const float* w_ih   = (const float*)d_in[7];
  const float* w_hh   = (const float*)d_in[8];
  const float* b_ih   = (const float*)d_in[9];
  const float* b_hh   = (const float*)d_in[10];

  char* ws = (char*)d_ws;
  float* msg = (float*)ws;                                        // 16 MB
  float* xg  = (float*)(ws + (size_t)NOBJ * DIMN * 4);            // 134 MB
  unsigned short* wbf = (unsigned short*)(ws + (size_t)(NOBJ + NPAIR) * DIMN * 4);
  unsigned short* wihb = wbf;
  unsigned short* whhb = wbf + 768 * 256;

  float* O = (float*)d_out;                 // objects section
  float* P = O + (size_t)NOBJ * DIMN;       // predicates section

  conv_w<<<384, 256, 0, stream>>>(w_ih, w_hh, wbf);

  const float* xo_cur = x_obj;
  const float* xp_cur = x_pred;
  for (int s = 0; s < 2; s++) {
    (void)hipMemsetAsync(msg, 0, (size_t)NOBJ * DIMN * 4, stream);
    gate_kernel<<<NPAIR / 4, 256, 0, stream>>>(xo_cur, xp_cur, pairs,
                                               w_e2v, b_e2v, w_v2e, b_v2e, msg, xg);
    gru_kernel<<<NOBJ / 64, 1024, 0, stream>>>(msg, xo_cur, wihb, whhb, b_ih, b_hh, O);
    gru_kernel<<<NPAIR / 64, 1024, 0, stream>>>(xg, xp_cur, wihb, whhb, b_ih, b_hh, P);
    xo_cur = O; xp_cur = P;
  }
}

// Round 2
// 1119.011 us; speedup vs baseline: 3.3682x; 3.3682x over previous
//
#include <hip/hip_runtime.h>
#include <hip/hip_bf16.h>

#define DIMN  256
#define NOBJ  16384
#define NPAIR 131072
#define NINC  (2 * NPAIR)

typedef float  floatx4 __attribute__((ext_vector_type(4)));
typedef __bf16 bf16x8  __attribute__((ext_vector_type(8)));

static __device__ __forceinline__ unsigned f2bf(float f) {
  unsigned u = __builtin_bit_cast(unsigned, f);
  u += 0x7FFFu + ((u >> 16) & 1u);          // round-to-nearest-even
  return u >> 16;
}
static __device__ __forceinline__ float sigmoidf_(float x) {
  return 1.0f / (1.0f + __expf(-x));
}
static __device__ __forceinline__ float tanhf_(float x) {
  return 1.0f - 2.0f / (1.0f + __expf(2.0f * x));
}
static __device__ __forceinline__ float dot4(float4 a, float4 b) {
  return a.x*b.x + a.y*b.y + a.z*b.z + a.w*b.w;
}
static __device__ __forceinline__ float4 relu4(float4 a) {
  float4 r; r.x = fmaxf(a.x,0.f); r.y = fmaxf(a.y,0.f);
  r.z = fmaxf(a.z,0.f); r.w = fmaxf(a.w,0.f); return r;
}
static __device__ __forceinline__ floatx4 mfma16(bf16x8 a, bf16x8 b, floatx4 c) {
  return __builtin_amdgcn_mfma_f32_16x16x32_bf16(a, b, c, 0, 0, 0);
}

// ---------------------------------------------------------------------------
// weight fp32 -> bf16 (once per launch). out: [wih | whh] bf16, row-major.
__global__ __launch_bounds__(256) void conv_w(const float* __restrict__ wih,
                                              const float* __restrict__ whh,
                                              unsigned short* __restrict__ out) {
  int i = blockIdx.x * 256 + threadIdx.x;           // one float4 each; 98304 total
  float4 v;
  if (i < 49152) v = ((const float4*)wih)[i];
  else           v = ((const float4*)whh)[i - 49152];
  unsigned short* d = out + (size_t)i * 4;
  d[0] = (unsigned short)f2bf(v.x); d[1] = (unsigned short)f2bf(v.y);
  d[2] = (unsigned short)f2bf(v.z); d[3] = (unsigned short)f2bf(v.w);
}

// ---------------------------------------------------------------------------
// CSR build: histogram -> scan -> scatter. Incidence i (0..NINC): object
// pairs[i], pair p=i>>1, side i&1 (0=subj uses g_s, 1=obj uses g_o).
__global__ __launch_bounds__(256) void hist_kernel(const int* __restrict__ pairs,
                                                   int* __restrict__ cnt) {
  int i = blockIdx.x * 256 + threadIdx.x;
  atomicAdd(&cnt[pairs[i]], 1);
}

__global__ __launch_bounds__(1024) void scan_kernel(const int* __restrict__ cnt,
                                                    int* __restrict__ row_start,
                                                    int* __restrict__ cursor) {
  __shared__ int sums[1024];
  const int t = threadIdx.x;
  const int base = t * 16;
  int local[16];
  int s = 0;
  #pragma unroll
  for (int i = 0; i < 16; i++) { local[i] = s; s += cnt[base + i]; }
  sums[t] = s;
  __syncthreads();
  for (int off = 1; off < 1024; off <<= 1) {
    int v = (t >= off) ? sums[t - off] : 0;
    __syncthreads();
    sums[t] += v;
    __syncthreads();
  }
  const int prefix = (t == 0) ? 0 : sums[t - 1];
  #pragma unroll
  for (int i = 0; i < 16; i++) {
    int v = prefix + local[i];
    row_start[base + i] = v;
    cursor[base + i] = v;
  }
  if (t == 1023) row_start[16384] = sums[1023];
}

__global__ __launch_bounds__(256) void scatter_kernel(const int* __restrict__ pairs,
                                                      int* __restrict__ cursor,
                                                      int* __restrict__ entries) {
  int i = blockIdx.x * 256 + threadIdx.x;
  int pos = atomicAdd(&cursor[pairs[i]], 1);
  entries[pos] = i;
}

// ---------------------------------------------------------------------------
// Gate kernel: one wave per pair. Computes 4 gate scalars; writes
// xg = m_s2p + m_o2p (input to pred-GRU) and gbuf[2p]=g_s, gbuf[2p+1]=g_o.
// NO fp32 atomics.
__global__ __launch_bounds__(256) void gate_kernel(
    const float* __restrict__ xobj, const float* __restrict__ xpred,
    const int* __restrict__ pairs,
    const float* __restrict__ w_e2v, const float* __restrict__ b_e2v,
    const float* __restrict__ w_v2e, const float* __restrict__ b_v2e,
    float* __restrict__ gbuf, float* __restrict__ xg)
{
  const int wave = threadIdx.x >> 6;
  const int lane = threadIdx.x & 63;
  const int p = blockIdx.x * 4 + wave;
  const int s = pairs[2*p], o = pairs[2*p+1];

  float4 vp = ((const float4*)(xpred + (size_t)p*DIMN))[lane];
  float4 vs = ((const float4*)(xobj  + (size_t)s*DIMN))[lane];
  float4 vo = ((const float4*)(xobj  + (size_t)o*DIMN))[lane];
  float4 we0 = ((const float4*)w_e2v)[lane];
  float4 we1 = ((const float4*)w_e2v)[64 + lane];
  float4 wv0 = ((const float4*)w_v2e)[lane];
  float4 wv1 = ((const float4*)w_v2e)[64 + lane];

  float4 rp = relu4(vp), rs = relu4(vs), ro = relu4(vo);
  float t0 = dot4(rs, we0);
  float t1 = dot4(ro, we0);
  float t2 = dot4(rp, we1);
  float t3 = dot4(rp, wv0);
  float t4 = dot4(rs, wv1);
  float t5 = dot4(ro, wv1);
  #pragma unroll
  for (int off = 32; off >= 1; off >>= 1) {
    t0 += __shfl_xor(t0, off); t1 += __shfl_xor(t1, off);
    t2 += __shfl_xor(t2, off); t3 += __shfl_xor(t3, off);
    t4 += __shfl_xor(t4, off); t5 += __shfl_xor(t5, off);
  }
  const float be = b_e2v[0], bv = b_v2e[0];
  const float g_s  = sigmoidf_(t0 + t2 + be);
  const float g_o  = sigmoidf_(t1 + t2 + be);
  const float g_sp = sigmoidf_(t3 + t4 + bv);
  const float g_op = sigmoidf_(t3 + t5 + bv);

  float4 xgv;
  xgv.x = vs.x*g_sp + vo.x*g_op; xgv.y = vs.y*g_sp + vo.y*g_op;
  xgv.z = vs.z*g_sp + vo.z*g_op; xgv.w = vs.w*g_sp + vo.w*g_op;
  ((float4*)(xg + (size_t)p*DIMN))[lane] = xgv;

  if (lane == 0) { gbuf[2*p] = g_s; gbuf[2*p+1] = g_o; }
}

// ---------------------------------------------------------------------------
// Gather segment-sum: one wave per object. msg[i] = sum over incident
// entries e of gbuf[e] * x_pred[e>>1]. Writes every row (no memset needed).
__global__ __launch_bounds__(256) void gather_kernel(
    const float* __restrict__ xpred, const float* __restrict__ gbuf,
    const int* __restrict__ row_start, const int* __restrict__ entries,
    float* __restrict__ msg)
{
  const int wave = threadIdx.x >> 6;
  const int lane = threadIdx.x & 63;
  const int obj = blockIdx.x * 4 + wave;
  const int s0 = row_start[obj], s1 = row_start[obj + 1];

  float4 acc = {0.f, 0.f, 0.f, 0.f};
  int inc = (s0 < s1) ? entries[s0] : 0;
  for (int e = s0; e < s1; e++) {
    int ninc = (e + 1 < s1) ? entries[e + 1] : 0;   // prefetch next index
    float g = gbuf[inc];
    float4 v = ((const float4*)(xpred + (size_t)(inc >> 1) * DIMN))[lane];
    acc.x += g * v.x; acc.y += g * v.y; acc.z += g * v.z; acc.w += g * v.w;
    inc = ninc;
  }
  ((float4*)(msg + (size_t)obj * DIMN))[lane] = acc;
}

// ---------------------------------------------------------------------------
// Fused GRU v2. Block = 64 rows x 256 cols, 16 waves; wave w owns cols
// [16w,16w+16) for ALL 64 rows (4 M-tiles) and all 6 weight streams ->
// every B fragment loaded by exactly one wave (no redundancy).
// Full A (X,H as bf16) staged in LDS once; single barrier; K-loop has no
// syncthreads so the compiler can pipeline B-loads/ds_reads/MFMA freely.
#define ASTR 264   // ushorts per LDS A-row (528 B; 16B-aligned, breaks pow2 banks)
__global__ __launch_bounds__(1024) void gru_kernel(
    const float* __restrict__ X, const float* __restrict__ H,
    const unsigned short* __restrict__ Wih, const unsigned short* __restrict__ Whh,
    const float* __restrict__ b_ih, const float* __restrict__ b_hh,
    float* __restrict__ OUT)
{
  __shared__ unsigned short Xs[64 * ASTR];
  __shared__ unsigned short Hs[64 * ASTR];

  const int tid  = threadIdx.x;
  const int lane = tid & 63;
  const int wave = tid >> 6;          // 0..15 -> col group of 16
  const int quad = lane >> 4;
  const int l16  = lane & 15;
  const int rowBase = blockIdx.x * 64;
  const int col = wave * 16 + l16;

  // ---- stage A: 64 rows x 256 fp32 -> bf16 LDS, both X and H ----
  {
    const int r  = tid >> 4;          // row 0..63
    const int c0 = tid & 15;          // 16 threads per row
    const float* xr = X + (size_t)(rowBase + r) * DIMN;
    const float* hr = H + (size_t)(rowBase + r) * DIMN;
    unsigned short* xd = Xs + r * ASTR;
    unsigned short* hd = Hs + r * ASTR;
    #pragma unroll
    for (int it = 0; it < 4; it++) {
      const int c = c0 + it * 16;     // float4 index within row (0..63)
      float4 v = ((const float4*)xr)[c];
      uint2 pk;
      pk.x = f2bf(v.x) | (f2bf(v.y) << 16);
      pk.y = f2bf(v.z) | (f2bf(v.w) << 16);
      *(uint2*)(xd + c * 4) = pk;
      v = ((const float4*)hr)[c];
      pk.x = f2bf(v.x) | (f2bf(v.y) << 16);
      pk.y = f2bf(v.z) | (f2bf(v.w) << 16);
      *(uint2*)(hd + c * 4) = pk;
    }
  }
  __syncthreads();

  floatx4 ar[4], az[4], an[4], ah[4];
  #pragma unroll
  for (int mt = 0; mt < 4; mt++) {
    ar[mt] = (floatx4){0,0,0,0}; az[mt] = (floatx4){0,0,0,0};
    an[mt] = (floatx4){0,0,0,0}; ah[mt] = (floatx4){0,0,0,0};
  }

  const unsigned short* wi = Wih + (size_t)col * DIMN;   // r gate; +256*DIMN z; +512*DIMN n
  const unsigned short* wh = Whh + (size_t)col * DIMN;
  const int kq = quad << 3;

  #pragma unroll
  for (int kc = 0; kc < 8; kc++) {
    const int k0 = kc * 32 + kq;
    bf16x8 bri = *(const bf16x8*)(wi + k0);
    bf16x8 bzi = *(const bf16x8*)(wi + 256*DIMN + k0);
    bf16x8 bni = *(const bf16x8*)(wi + 512*DIMN + k0);
    bf16x8 brh = *(const bf16x8*)(wh + k0);
    bf16x8 bzh = *(const bf16x8*)(wh + 256*DIMN + k0);
    bf16x8 bnh = *(const bf16x8*)(wh + 512*DIMN + k0);
    #pragma unroll
    for (int mt = 0; mt < 4; mt++) {
      const int ao = (mt*16 + l16) * ASTR + kc * 32 + kq;
      bf16x8 aX = *(const bf16x8*)(Xs + ao);
      bf16x8 aH = *(const bf16x8*)(Hs + ao);
      ar[mt] = mfma16(aX, bri, ar[mt]);
      ar[mt] = mfma16(aH, brh, ar[mt]);
      az[mt] = mfma16(aX, bzi, az[mt]);
      az[mt] = mfma16(aH, bzh, az[mt]);
      an[mt] = mfma16(aX, bni, an[mt]);
      ah[mt] = mfma16(aH, bnh, ah[mt]);
    }
  }

  // epilogue: C layout col=lane&15, row=quad*4+v (m89-verified)
  const float br  = b_ih[col]       + b_hh[col];
  const float bz  = b_ih[col + 256] + b_hh[col + 256];
  const float bin = b_ih[col + 512];
  const float bhn = b_hh[col + 512];
  #pragma unroll
  for (int mt = 0; mt < 4; mt++) {
    #pragma unroll
    for (int v = 0; v < 4; v++) {
      const int m = rowBase + mt*16 + (quad << 2) + v;
      const size_t idx = (size_t)m * DIMN + col;
      const float r_ = sigmoidf_(ar[mt][v] + br);
      const float z_ = sigmoidf_(az[mt][v] + bz);
      const float n_ = tanhf_(an[mt][v] + bin + r_ * (ah[mt][v] + bhn));
      OUT[idx] = (1.0f - z_) * n_ + z_ * H[idx];
    }
  }
}

// ---------------------------------------------------------------------------
extern "C" void kernel_launch(void* const* d_in, const int* in_sizes, int n_in,
                              void* d_out, int out_size, void* d_ws, size_t ws_size,
                              hipStream_t stream) {
  const float* x_obj  = (const float*)d_in[0];
  const float* x_pred = (const float*)d_in[1];
  const int*   pairs  = (const int*)d_in[2];
  const float* w_e2v  = (const float*)d_in[3];
  const float* b_e2v  = (const float*)d_in[4];
  const float* w_v2e  = (const float*)d_in[5];
  const float* b_v2e  = (const float*)d_in[6];
  const float* w_ih   = (const float*)d_in[7];
  const float* w_hh   = (const float*)d_in[8];
  const float* b_ih   = (const float*)d_in[9];
  const float* b_hh   = (const float*)d_in[10];

  char* ws = (char*)d_ws;
  size_t off = 0;
  float* msg = (float*)(ws + off); off += (size_t)NOBJ * DIMN * 4;     // 16 MB
  float* xg  = (float*)(ws + off); off += (size_t)NPAIR * DIMN * 4;    // 134 MB
  unsigned short* wbf = (unsigned short*)(ws + off); off += (size_t)2 * 768 * 256 * 2; // 786 KB
  float* gbuf = (float*)(ws + off); off += (size_t)NINC * 4;           // 1 MB
  int* row_start = (int*)(ws + off); off += (size_t)(NOBJ + 2) * 4;
  int* entries   = (int*)(ws + off); off += (size_t)NINC * 4;          // 1 MB
  // cnt & cursor only live during CSR build -> alias into msg region
  int* cnt    = (int*)msg;
  int* cursor = (int*)msg + NOBJ;

  unsigned short* wihb = wbf;
  unsigned short* whhb = wbf + 768 * 256;

  float* O = (float*)d_out;                 // objects section
  float* P = O + (size_t)NOBJ * DIMN;       // predicates section

  conv_w<<<384, 256, 0, stream>>>(w_ih, w_hh, wbf);

  // CSR build (pairs are launch-constant; rebuilt every call for graph safety)
  (void)hipMemsetAsync(cnt, 0, NOBJ * sizeof(int), stream);
  hist_kernel<<<NINC / 256, 256, 0, stream>>>(pairs, cnt);
  scan_kernel<<<1, 1024, 0, stream>>>(cnt, row_start, cursor);
  scatter_kernel<<<NINC / 256, 256, 0, stream>>>(pairs, cursor, entries);

  const float* xo_cur = x_obj;
  const float* xp_cur = x_pred;
  for (int s = 0; s < 2; s++) {
    gate_kernel<<<NPAIR / 4, 256, 0, stream>>>(xo_cur, xp_cur, pairs,
                                               w_e2v, b_e2v, w_v2e, b_v2e, gbuf, xg);
    gather_kernel<<<NOBJ / 4, 256, 0, stream>>>(xp_cur, gbuf, row_start, entries, msg);
    gru_kernel<<<NOBJ / 64, 1024, 0, stream>>>(msg, xo_cur, wihb, whhb, b_ih, b_hh, O);
    gru_kernel<<<NPAIR / 64, 1024, 0, stream>>>(xg, xp_cur, wihb, whhb, b_ih, b_hh, P);
    xo_cur = O; xp_cur = P;
  }
}